// Round 19
// baseline (67.665 us; speedup 1.0000x reference)
//
#include <hip/hip_runtime.h>
#include <hip/hip_bf16.h>
#include <cstddef>
#include <cstdint>

#define BB 4
#define CC 256
#define II 32
#define NN 4096

// 1/sqrt(32) * log2(e): fold softmax scale AND exp->exp2 conversion into q.
#define SCALE_Q 0.25505572751402893f

typedef __attribute__((ext_vector_type(8))) short bf16x8;
typedef __attribute__((ext_vector_type(16))) float f32x16;

static __device__ __forceinline__ int cvt_pk_bf16(float lo, float hi) {
  int d;
  asm("v_cvt_pk_bf16_f32 %0, %1, %2" : "=v"(d) : "v"(lo), "v"(hi));
  return d;
}
static __device__ __forceinline__ void perm32swap_f(float& a, float& b) {
  asm("v_permlane32_swap_b32 %0, %1" : "+v"(a), "+v"(b));
}
static __device__ __forceinline__ float max3f(float a, float b, float c) {
  float d;
  asm("v_max3_f32 %0, %1, %2, %3" : "=v"(d) : "v"(a), "v"(b), "v"(c));
  return d;
}
static __device__ __forceinline__ f32x16 zero16() {
  f32x16 z;
#pragma unroll
  for (int i = 0; i < 16; ++i) z[i] = 0.0f;
  return z;
}
// VGPR-form S-MFMA (softmax operand stays out of AGPRs).
static __device__ __forceinline__ void mfma_bf16_first(bf16x8 a, bf16x8 b, f32x16& c) {
  asm("s_nop 1\n\tv_mfma_f32_32x32x16_bf16 %0, %1, %2, %0"
      : "+v"(c) : "v"(a), "v"(b));
}
static __device__ __forceinline__ void mfma_bf16_last(bf16x8 a, bf16x8 b, f32x16& c) {
  asm("v_mfma_f32_32x32x16_bf16 %0, %1, %2, %0\n\ts_nop 7\n\ts_nop 7"
      : "+v"(c) : "v"(a), "v"(b));
}
static __device__ __forceinline__ bf16x8 pack8(float f0, float f1, float f2,
    float f3, float f4, float f5, float f6, float f7) {
  union { int w[4]; bf16x8 v8; } u;
  u.w[0] = cvt_pk_bf16(f0, f1);
  u.w[1] = cvt_pk_bf16(f2, f3);
  u.w[2] = cvt_pk_bf16(f4, f5);
  u.w[3] = cvt_pk_bf16(f6, f7);
  return u.v8;
}
static __device__ __forceinline__ ushort f2bfu(float f) {
  union { __hip_bfloat16 h; ushort u; } cv;
  cv.h = __float2bfloat16(f);
  return cv.u;
}
static __device__ __forceinline__ int pack4_fp8(float a, float b, float c, float d) {
  int r = __builtin_amdgcn_cvt_pk_fp8_f32(a, b, 0, false);
  r = __builtin_amdgcn_cvt_pk_fp8_f32(c, d, r, true);
  return r;
}
static __device__ __forceinline__ unsigned char f2fp8(float f) {
  return (unsigned char)(__builtin_amdgcn_cvt_pk_fp8_f32(f, f, 0, false) & 0xff);
}

// Layouts:
//  qT/kT (bf16): [b][mt=n/32][frag=i/16][p]; p = 256*((i>>3)&1) + 8*(n&31) + (i&7)
//  vT8  (fp8):   [b][ct=c/32][nt=n/16][p];  p = 256*((n>>3)&1) + 8*(c&31) + (n&7)
//  wpre (bf16):  [g][ks][lane*8+j]; g: 0=Wq, 1=Wk, 2..9=Wv rows (g-2)*32..

// ---- W prepack (run once) --------------------------------------------------
__global__ __launch_bounds__(64) void prepack_w(
    const float* __restrict__ Wq, const float* __restrict__ Wk,
    const float* __restrict__ Wv, ushort* __restrict__ wpre) {
  const int g = blockIdx.x;   // 0..9
  const int ks = blockIdx.y;  // 0..15
  const int lane = threadIdx.x;
  const int l31 = lane & 31;
  const int h = lane >> 5;
  const float* src = (g == 0) ? (Wq + (size_t)l31 * CC)
                   : (g == 1) ? (Wk + (size_t)l31 * CC)
                              : (Wv + (size_t)((g - 2) * 32 + l31) * CC);
  const int c = ks * 16 + h * 8;
  const float4 a = *(const float4*)(src + c);
  const float4 b = *(const float4*)(src + c + 4);
  union { ushort us[8]; int4 i4; } pk;
  pk.us[0] = f2bfu(a.x); pk.us[1] = f2bfu(a.y);
  pk.us[2] = f2bfu(a.z); pk.us[3] = f2bfu(a.w);
  pk.us[4] = f2bfu(b.x); pk.us[5] = f2bfu(b.y);
  pk.us[6] = f2bfu(b.z); pk.us[7] = f2bfu(b.w);
  *(int4*)(wpre + ((size_t)g * 16 + ks) * 512 + lane * 8) = pk.i4;
}

// ---- fused qkv projection, LDS-staged x + prepacked W (r18, unchanged) -----
__global__ __launch_bounds__(320, 2) void proj_lds(
    const float* __restrict__ bq, const float* __restrict__ bk,
    const float* __restrict__ bv, const float* __restrict__ x,
    const ushort* __restrict__ wpre,
    ushort* __restrict__ qT, ushort* __restrict__ kT,
    unsigned char* __restrict__ vT8) {
  __shared__ float xs[256 * 32];

  const int tid = threadIdx.x;
  const int w = tid >> 6;
  const int lane = tid & 63;
  const int l31 = lane & 31;
  const int h = lane >> 5;
  const int b = blockIdx.x;
  const int n0 = blockIdx.y * 32;

  {
    const float* xb = x + (size_t)b * CC * NN + n0;
    for (int i = w; i < 32; i += 5) {
      const float* src = xb + (size_t)(i * 8 + (lane >> 3)) * NN + (lane & 7) * 4;
      const float4 v = *(const float4*)src;
      *(float4*)&xs[i * 256 + lane * 4] = v;
    }
  }
  __syncthreads();

  const ushort* wp0 = wpre + (size_t)((w == 0) ? 0 : (2 + (w - 1) * 2)) * 16 * 512 + lane * 8;
  const ushort* wp1 = wp0 + 16 * 512;

  f32x16 acc0 = zero16(), acc1 = zero16();
#pragma unroll 4
  for (int ks = 0; ks < 16; ++ks) {
    const int c = ks * 16 + h * 8;
    const float* xp = &xs[c * 32 + l31];
    bf16x8 xf = pack8(xp[0], xp[32], xp[64], xp[96],
                      xp[128], xp[160], xp[192], xp[224]);
    const bf16x8 wf0 = *reinterpret_cast<const bf16x8*>(wp0 + ks * 512);
    const bf16x8 wf1 = *reinterpret_cast<const bf16x8*>(wp1 + ks * 512);
    acc0 = __builtin_amdgcn_mfma_f32_32x32x16_bf16(wf0, xf, acc0, 0, 0, 0);
    acc1 = __builtin_amdgcn_mfma_f32_32x32x16_bf16(wf1, xf, acc1, 0, 0, 0);
  }

  if (w == 0) {
    ushort* qb = qT + (size_t)(b * 128 + (n0 >> 5)) * 1024;
    ushort* kb = kT + (size_t)(b * 128 + (n0 >> 5)) * 1024;
#pragma unroll
    for (int r = 0; r < 16; ++r) {
      const int i = (r & 3) + 8 * (r >> 2) + 4 * h;
      const size_t off = (size_t)(i >> 4) * 512 + ((i >> 3) & 1) * 256 + 8 * l31 + (i & 7);
      qb[off] = f2bfu((acc0[r] + bq[i]) * SCALE_Q);
      kb[off] = f2bfu(acc1[r] + bk[i]);
    }
  } else {
    const int n = n0 + l31;
    const size_t nsub = (size_t)(n >> 4) * 512 + ((size_t)((n >> 3) & 1)) * 256 + (n & 7);
    const size_t bbase = (size_t)b * (1 << 20);
#pragma unroll
    for (int r = 0; r < 16; ++r) {
      const int rp = (r & 3) + 8 * (r >> 2) + 4 * h;
      const int c0 = (w - 1) * 64 + rp;
      const int c1 = c0 + 32;
      vT8[bbase + (size_t)(c0 >> 5) * 131072 + nsub + (c0 & 31) * 8] = f2fp8(acc0[r] + bv[c0]);
      vT8[bbase + (size_t)(c1 >> 5) * 131072 + nsub + (c1 & 31) * 8] = f2fp8(acc1[r] + bv[c1]);
    }
  }
}

// ---- flash attention: producer-consumer wave specialization ----------------
// grid 512, block 512. Waves 0-3 = PRODUCERS: wave p owns keys [p*64,+64) per
// 256-key tile; S bf16-MFMA + block softmax -> pbuf/fbuf (K prefetched 1 tile
// ahead). Waves 4-7 = CONSUMERS: wave c owns channels [c*64,+64); near-pure
// fp8-MFMA PV stream at setprio(1), consuming pbuf one tile behind.
__global__ __launch_bounds__(512, 4) void flash_pc(
    const ushort* __restrict__ qT, const ushort* __restrict__ kT,
    const unsigned char* __restrict__ vT8, const float* __restrict__ x,
    const float* __restrict__ gamma, float* __restrict__ out) {
  __shared__ __align__(16) unsigned char pbuf[2][32 * 264];  // P fp8 [q][key]
  __shared__ float mlds[144];     // producer wave-max [p*33+q]
  __shared__ float slds[144];     // producer part-sum [p*33+q]
  __shared__ float fbuf[2][32];   // per-tile rescale factor per q
  __shared__ float lbuf[32];      // final l per q

  const int tid = threadIdx.x;
  const int lane = tid & 63;
  const int w = tid >> 6;
  const int q = lane & 31;
  const int h = lane >> 5;
  const bool prod = (w < 4);
  const int p = w & 3;            // producer segment / consumer pair index

  const int wg = blockIdx.x;
  const int xcd = wg & 7;
  const int b = xcd >> 1;
  const int nt = ((xcd & 1) << 6) + (wg >> 3);
  const int n0 = nt * 32;

  const ushort* ktb = kT + (size_t)b * 128 * 1024;

  // ---------------- producer state ----------------
  bf16x8 qf0 = {}, qf1 = {};
  bf16x8 kA0 = {}, kA1 = {}, kB0 = {}, kB1 = {};  // current tile K frags
  float m_run = -1e30f, l_run = 0.0f;
  if (prod) {
    const ushort* qb = qT + (size_t)(b * 128 + nt) * 1024 + lane * 8;
    qf0 = *reinterpret_cast<const bf16x8*>(qb);
    qf1 = *reinterpret_cast<const bf16x8*>(qb + 512);
    const ushort* kc = ktb + (size_t)(p * 2) * 1024 + lane * 8;   // tile 0
    kA0 = *reinterpret_cast<const bf16x8*>(kc);
    kA1 = *reinterpret_cast<const bf16x8*>(kc + 512);
    kB0 = *reinterpret_cast<const bf16x8*>(kc + 1024);
    kB1 = *reinterpret_cast<const bf16x8*>(kc + 1536);
  }

  // ---------------- consumer state ----------------
  f32x16 accA = zero16(), accB = zero16();
  const unsigned char* vtbA = vT8 + ((size_t)b << 20) + (size_t)(2 * p) * 131072 + lane * 8;
  const unsigned char* vtbB = vtbA + 131072;
  if (!prod) __builtin_amdgcn_s_setprio(1);

  // ================= prologue: tile 0 =================
  if (prod) {
    f32x16 st0 = zero16(), st1 = zero16();
    mfma_bf16_first(kA0, qf0, st0);
    mfma_bf16_first(kB0, qf0, st1);
    mfma_bf16_last(kA1, qf1, st0);
    mfma_bf16_last(kB1, qf1, st1);
    // prefetch K(1)
    const ushort* kn = ktb + (size_t)(8 + p * 2) * 1024 + lane * 8;
    kA0 = *reinterpret_cast<const bf16x8*>(kn);
    kA1 = *reinterpret_cast<const bf16x8*>(kn + 512);
    kB0 = *reinterpret_cast<const bf16x8*>(kn + 1024);
    kB1 = *reinterpret_cast<const bf16x8*>(kn + 1536);
    // wave max over both subtiles
    float a0 = max3f(st0[0], st0[1], st0[2]);
    float a1 = max3f(st0[3], st0[4], st0[5]);
    float a2 = max3f(st0[6], st0[7], st0[8]);
    float a3 = max3f(st0[9], st0[10], st0[11]);
    a0 = max3f(st0[12], st0[13], a0);
    a1 = max3f(st0[14], st0[15], a1);
    a2 = max3f(st1[0], st1[1], a2);
    a3 = max3f(st1[2], st1[3], a3);
    a0 = max3f(st1[4], st1[5], a0);
    a1 = max3f(st1[6], st1[7], a1);
    a2 = max3f(st1[8], st1[9], a2);
    a3 = max3f(st1[10], st1[11], a3);
    a0 = max3f(st1[12], st1[13], a0);
    a1 = max3f(st1[14], st1[15], a1);
    float mx = max3f(a0, a1, fmaxf(a2, a3));
    float sw1 = mx, sw2 = mx;
    perm32swap_f(sw1, sw2);
    if (lane < 32) mlds[p * 33 + q] = fmaxf(sw1, sw2);
    __syncthreads();  // B1(0)
    float tmax = fmaxf(fmaxf(mlds[q], mlds[33 + q]),
                       fmaxf(mlds[66 + q], mlds[99 + q]));
    m_run = tmax;
#pragma unroll
    for (int r = 0; r < 16; ++r) st0[r] = __builtin_amdgcn_exp2f(st0[r] - m_run);
#pragma unroll
    for (int r = 0; r < 16; ++r) st1[r] = __builtin_amdgcn_exp2f(st1[r] - m_run);
    float s0 = ((st0[0] + st0[1]) + (st0[2] + st0[3])) +
               ((st0[4] + st0[5]) + (st0[6] + st0[7])) +
               ((st0[8] + st0[9]) + (st0[10] + st0[11])) +
               ((st0[12] + st0[13]) + (st0[14] + st0[15]));
    float s1 = ((st1[0] + st1[1]) + (st1[2] + st1[3])) +
               ((st1[4] + st1[5]) + (st1[6] + st1[7])) +
               ((st1[8] + st1[9]) + (st1[10] + st1[11])) +
               ((st1[12] + st1[13]) + (st1[14] + st1[15]));
    float ps = s0 + s1, pa = ps, pb2 = ps;
    perm32swap_f(pa, pb2);
    if (lane < 32) slds[p * 33 + q] = pa + pb2;
#pragma unroll
    for (int rg = 0; rg < 4; ++rg) {
      const int pk0 = pack4_fp8(st0[rg * 4], st0[rg * 4 + 1], st0[rg * 4 + 2], st0[rg * 4 + 3]);
      *reinterpret_cast<int*>(&pbuf[0][q * 264 + p * 64 + rg * 8 + h * 4]) = pk0;
      const int pk1 = pack4_fp8(st1[rg * 4], st1[rg * 4 + 1], st1[rg * 4 + 2], st1[rg * 4 + 3]);
      *reinterpret_cast<int*>(&pbuf[0][q * 264 + p * 64 + 32 + rg * 8 + h * 4]) = pk1;
    }
    if (p == 0 && lane < 32) fbuf[0][q] = 1.0f;
    __syncthreads();  // B2(0)
    l_run = slds[q] + slds[33 + q] + slds[66 + q] + slds[99 + q];
  } else {
    __syncthreads();  // B1(0)
    __syncthreads();  // B2(0)
  }

  // ================= main loop: t = 1..15 =================
  for (int t = 1; t < 16; ++t) {
    if (!prod) {
      // ---- consumer: rescale + PV(t-1), pure MFMA stream ----
      const int slot = (t - 1) & 1;
      const float f = fbuf[slot][q];
      if (__any(f != 1.0f)) {
#pragma unroll
        for (int r = 0; r < 16; ++r) { accA[r] *= f; accB[r] *= f; }
      }
      const unsigned char* pb = &pbuf[slot][q * 264 + h * 8];
      const unsigned char* vA = vtbA + (size_t)((t - 1) * 16) * 512;
      const unsigned char* vB = vtbB + (size_t)((t - 1) * 16) * 512;
#pragma unroll
      for (int kt = 0; kt < 16; ++kt) {
        const long pf = *reinterpret_cast<const long*>(pb + kt * 16);
        const long va = *reinterpret_cast<const long*>(vA + kt * 512);
        accA = __builtin_amdgcn_mfma_f32_32x32x16_fp8_fp8(va, pf, accA, 0, 0, 0);
        const long vb = *reinterpret_cast<const long*>(vB + kt * 512);
        accB = __builtin_amdgcn_mfma_f32_32x32x16_fp8_fp8(vb, pf, accB, 0, 0, 0);
      }
      __syncthreads();  // B1(t)
      __syncthreads();  // B2(t)
    } else {
      // ---- producer: S(t) + softmax(t) -> pbuf[t&1] ----
      f32x16 st0 = zero16(), st1 = zero16();
      mfma_bf16_first(kA0, qf0, st0);
      mfma_bf16_first(kB0, qf0, st1);
      mfma_bf16_last(kA1, qf1, st0);
      mfma_bf16_last(kB1, qf1, st1);
      // prefetch K(t+1)
      if (t < 15) {
        const ushort* kn = ktb + (size_t)((t + 1) * 8 + p * 2) * 1024 + lane * 8;
        kA0 = *reinterpret_cast<const bf16x8*>(kn);
        kA1 = *reinterpret_cast<const bf16x8*>(kn + 512);
        kB0 = *reinterpret_cast<const bf16x8*>(kn + 1024);
        kB1 = *reinterpret_cast<const bf16x8*>(kn + 1536);
      }
      float a0 = max3f(st0[0], st0[1], st0[2]);
      float a1 = max3f(st0[3], st0[4], st0[5]);
      float a2 = max3f(st0[6], st0[7], st0[8]);
      float a3 = max3f(st0[9], st0[10], st0[11]);
      a0 = max3f(st0[12], st0[13], a0);
      a1 = max3f(st0[14], st0[15], a1);
      a2 = max3f(st1[0], st1[1], a2);
      a3 = max3f(st1[2], st1[3], a3);
      a0 = max3f(st1[4], st1[5], a0);
      a1 = max3f(st1[6], st1[7], a1);
      a2 = max3f(st1[8], st1[9], a2);
      a3 = max3f(st1[10], st1[11], a3);
      a0 = max3f(st1[12], st1[13], a0);
      a1 = max3f(st1[14], st1[15], a1);
      float mx = max3f(a0, a1, fmaxf(a2, a3));
      float sw1 = mx, sw2 = mx;
      perm32swap_f(sw1, sw2);
      if (lane < 32) mlds[p * 33 + q] = fmaxf(sw1, sw2);
      __syncthreads();  // B1(t)
      float tmax = fmaxf(fmaxf(mlds[q], mlds[33 + q]),
                         fmaxf(mlds[66 + q], mlds[99 + q]));
      float f = 1.0f;
      if (__any(tmax > m_run + 8.0f)) {
        const float mnew = fmaxf(m_run, tmax);
        f = __builtin_amdgcn_exp2f(m_run - mnew);
        l_run *= f;
        m_run = mnew;
      }
      if (p == 0 && lane < 32) fbuf[t & 1][q] = f;
#pragma unroll
      for (int r = 0; r < 16; ++r) st0[r] = __builtin_amdgcn_exp2f(st0[r] - m_run);
#pragma unroll
      for (int r = 0; r < 16; ++r) st1[r] = __builtin_amdgcn_exp2f(st1[r] - m_run);
      float s0 = ((st0[0] + st0[1]) + (st0[2] + st0[3])) +
                 ((st0[4] + st0[5]) + (st0[6] + st0[7])) +
                 ((st0[8] + st0[9]) + (st0[10] + st0[11])) +
                 ((st0[12] + st0[13]) + (st0[14] + st0[15]));
      float s1 = ((st1[0] + st1[1]) + (st1[2] + st1[3])) +
                 ((st1[4] + st1[5]) + (st1[6] + st1[7])) +
                 ((st1[8] + st1[9]) + (st1[10] + st1[11])) +
                 ((st1[12] + st1[13]) + (st1[14] + st1[15]));
      float ps = s0 + s1, pa = ps, pb2 = ps;
      perm32swap_f(pa, pb2);
      if (lane < 32) slds[p * 33 + q] = pa + pb2;
#pragma unroll
      for (int rg = 0; rg < 4; ++rg) {
        const int pk0 = pack4_fp8(st0[rg * 4], st0[rg * 4 + 1], st0[rg * 4 + 2], st0[rg * 4 + 3]);
        *reinterpret_cast<int*>(&pbuf[t & 1][q * 264 + p * 64 + rg * 8 + h * 4]) = pk0;
        const int pk1 = pack4_fp8(st1[rg * 4], st1[rg * 4 + 1], st1[rg * 4 + 2], st1[rg * 4 + 3]);
        *reinterpret_cast<int*>(&pbuf[t & 1][q * 264 + p * 64 + 32 + rg * 8 + h * 4]) = pk1;
      }
      __syncthreads();  // B2(t)
      l_run += slds[q] + slds[33 + q] + slds[66 + q] + slds[99 + q];
    }
  }

  // ================= tail =================
  if (!prod) {
    const float f = fbuf[1][q];
    if (__any(f != 1.0f)) {
#pragma unroll
      for (int r = 0; r < 16; ++r) { accA[r] *= f; accB[r] *= f; }
    }
    const unsigned char* pb = &pbuf[1][q * 264 + h * 8];
    const unsigned char* vA = vtbA + (size_t)(15 * 16) * 512;
    const unsigned char* vB = vtbB + (size_t)(15 * 16) * 512;
#pragma unroll
    for (int kt = 0; kt < 16; ++kt) {
      const long pf = *reinterpret_cast<const long*>(pb + kt * 16);
      const long va = *reinterpret_cast<const long*>(vA + kt * 512);
      accA = __builtin_amdgcn_mfma_f32_32x32x16_fp8_fp8(va, pf, accA, 0, 0, 0);
      const long vb = *reinterpret_cast<const long*>(vB + kt * 512);
      accB = __builtin_amdgcn_mfma_f32_32x32x16_fp8_fp8(vb, pf, accB, 0, 0, 0);
    }
  } else {
    if (p == 0 && lane < 32) lbuf[q] = l_run;
  }
  __syncthreads();  // B3: lbuf visible

  if (!prod) {
    const float g = gamma[0];
    const float linv = 1.0f / lbuf[q];
#pragma unroll
    for (int r = 0; r < 16; ++r) {
      const int rp = (r & 3) + 8 * (r >> 2) + 4 * h;
      const int c0 = p * 64 + rp;
      const size_t i0 = ((size_t)b * CC + c0) * NN + n0 + q;
      const size_t i1 = ((size_t)b * CC + c0 + 32) * NN + n0 + q;
      out[i0] = g * accA[r] * linv + x[i0];
      out[i1] = g * accB[r] * linv + x[i1];
    }
  }
}

extern "C" void kernel_launch(void* const* d_in, const int* in_sizes, int n_in,
                              void* d_out, int out_size, void* d_ws, size_t ws_size,
                              hipStream_t stream) {
  const float* x = (const float*)d_in[0];
  const float* Wq = (const float*)d_in[1];
  const float* bq = (const float*)d_in[2];
  const float* Wk = (const float*)d_in[3];
  const float* bk = (const float*)d_in[4];
  const float* Wv = (const float*)d_in[5];
  const float* bv = (const float*)d_in[6];
  const float* gamma = (const float*)d_in[7];
  float* out = (float*)d_out;

  ushort* qT = (ushort*)d_ws;                          // B*128*1024 bf16
  ushort* kT = qT + (size_t)BB * 128 * 1024;           // B*128*1024 bf16
  unsigned char* vT8 = (unsigned char*)(kT + (size_t)BB * 128 * 1024);  // B*1MB fp8
  ushort* wpre = (ushort*)(vT8 + (size_t)BB * (1 << 20));  // 160 KB

  prepack_w<<<dim3(10, 16), dim3(64), 0, stream>>>(Wq, Wk, Wv, wpre);
  proj_lds<<<dim3(BB, NN / 32), dim3(320), 0, stream>>>(
      bq, bk, bv, x, wpre, qT, kT, vT8);
  flash_pc<<<dim3(512), dim3(512), 0, stream>>>(
      qT, kT, vT8, x, gamma, out);
}

// Round 20
// 66.631 us; speedup vs baseline: 1.0155x; 1.0155x over previous
//
#include <hip/hip_runtime.h>
#include <hip/hip_bf16.h>
#include <cstddef>
#include <cstdint>

#define BB 4
#define CC 256
#define II 32
#define NN 4096

// 1/sqrt(32) * log2(e): fold softmax scale AND exp->exp2 conversion into q.
#define SCALE_Q 0.25505572751402893f

typedef __attribute__((ext_vector_type(8))) short bf16x8;
typedef __attribute__((ext_vector_type(16))) float f32x16;

static __device__ __forceinline__ int cvt_pk_bf16(float lo, float hi) {
  int d;
  asm("v_cvt_pk_bf16_f32 %0, %1, %2" : "=v"(d) : "v"(lo), "v"(hi));
  return d;
}
static __device__ __forceinline__ void perm32swap_f(float& a, float& b) {
  asm("v_permlane32_swap_b32 %0, %1" : "+v"(a), "+v"(b));
}
static __device__ __forceinline__ float max3f(float a, float b, float c) {
  float d;
  asm("v_max3_f32 %0, %1, %2, %3" : "=v"(d) : "v"(a), "v"(b), "v"(c));
  return d;
}
static __device__ __forceinline__ f32x16 zero16() {
  f32x16 z;
#pragma unroll
  for (int i = 0; i < 16; ++i) z[i] = 0.0f;
  return z;
}
static __device__ __forceinline__ bf16x8 pack8(float f0, float f1, float f2,
    float f3, float f4, float f5, float f6, float f7) {
  union { int w[4]; bf16x8 v8; } u;
  u.w[0] = cvt_pk_bf16(f0, f1);
  u.w[1] = cvt_pk_bf16(f2, f3);
  u.w[2] = cvt_pk_bf16(f4, f5);
  u.w[3] = cvt_pk_bf16(f6, f7);
  return u.v8;
}
static __device__ __forceinline__ ushort f2bfu(float f) {
  union { __hip_bfloat16 h; ushort u; } cv;
  cv.h = __float2bfloat16(f);
  return cv.u;
}
static __device__ __forceinline__ int pack4_fp8(float a, float b, float c, float d) {
  int r = __builtin_amdgcn_cvt_pk_fp8_f32(a, b, 0, false);
  r = __builtin_amdgcn_cvt_pk_fp8_f32(c, d, r, true);
  return r;
}
static __device__ __forceinline__ unsigned char f2fp8(float f) {
  return (unsigned char)(__builtin_amdgcn_cvt_pk_fp8_f32(f, f, 0, false) & 0xff);
}

// Layouts:
//  qT/kT (bf16): [b][mt=n/32][frag=i/16][p]; p = 256*((i>>3)&1) + 8*(n&31) + (i&7)
//  vT8  (fp8):   [b][ct=c/32][nt=n/16][p];  p = 256*((n>>3)&1) + 8*(c&31) + (n&7)
//  wpre (bf16):  [g][ks][lane*8+j]; g: 0=Wq, 1=Wk, 2..9=Wv rows (g-2)*32..

// ---- W prepack (run once) --------------------------------------------------
__global__ __launch_bounds__(64) void prepack_w(
    const float* __restrict__ Wq, const float* __restrict__ Wk,
    const float* __restrict__ Wv, ushort* __restrict__ wpre) {
  const int g = blockIdx.x;   // 0..9
  const int ks = blockIdx.y;  // 0..15
  const int lane = threadIdx.x;
  const int l31 = lane & 31;
  const int h = lane >> 5;
  const float* src = (g == 0) ? (Wq + (size_t)l31 * CC)
                   : (g == 1) ? (Wk + (size_t)l31 * CC)
                              : (Wv + (size_t)((g - 2) * 32 + l31) * CC);
  const int c = ks * 16 + h * 8;
  const float4 a = *(const float4*)(src + c);
  const float4 b = *(const float4*)(src + c + 4);
  union { ushort us[8]; int4 i4; } pk;
  pk.us[0] = f2bfu(a.x); pk.us[1] = f2bfu(a.y);
  pk.us[2] = f2bfu(a.z); pk.us[3] = f2bfu(a.w);
  pk.us[4] = f2bfu(b.x); pk.us[5] = f2bfu(b.y);
  pk.us[6] = f2bfu(b.z); pk.us[7] = f2bfu(b.w);
  *(int4*)(wpre + ((size_t)g * 16 + ks) * 512 + lane * 8) = pk.i4;
}

// ---- fused qkv projection, LDS-staged x + prepacked W (r18, unchanged) -----
__global__ __launch_bounds__(320, 2) void proj_lds(
    const float* __restrict__ bq, const float* __restrict__ bk,
    const float* __restrict__ bv, const float* __restrict__ x,
    const ushort* __restrict__ wpre,
    ushort* __restrict__ qT, ushort* __restrict__ kT,
    unsigned char* __restrict__ vT8) {
  __shared__ float xs[256 * 32];

  const int tid = threadIdx.x;
  const int w = tid >> 6;
  const int lane = tid & 63;
  const int l31 = lane & 31;
  const int h = lane >> 5;
  const int b = blockIdx.x;
  const int n0 = blockIdx.y * 32;

  {
    const float* xb = x + (size_t)b * CC * NN + n0;
    for (int i = w; i < 32; i += 5) {
      const float* src = xb + (size_t)(i * 8 + (lane >> 3)) * NN + (lane & 7) * 4;
      const float4 v = *(const float4*)src;
      *(float4*)&xs[i * 256 + lane * 4] = v;
    }
  }
  __syncthreads();

  const ushort* wp0 = wpre + (size_t)((w == 0) ? 0 : (2 + (w - 1) * 2)) * 16 * 512 + lane * 8;
  const ushort* wp1 = wp0 + 16 * 512;

  f32x16 acc0 = zero16(), acc1 = zero16();
#pragma unroll 4
  for (int ks = 0; ks < 16; ++ks) {
    const int c = ks * 16 + h * 8;
    const float* xp = &xs[c * 32 + l31];
    bf16x8 xf = pack8(xp[0], xp[32], xp[64], xp[96],
                      xp[128], xp[160], xp[192], xp[224]);
    const bf16x8 wf0 = *reinterpret_cast<const bf16x8*>(wp0 + ks * 512);
    const bf16x8 wf1 = *reinterpret_cast<const bf16x8*>(wp1 + ks * 512);
    acc0 = __builtin_amdgcn_mfma_f32_32x32x16_bf16(wf0, xf, acc0, 0, 0, 0);
    acc1 = __builtin_amdgcn_mfma_f32_32x32x16_bf16(wf1, xf, acc1, 0, 0, 0);
  }

  if (w == 0) {
    ushort* qb = qT + (size_t)(b * 128 + (n0 >> 5)) * 1024;
    ushort* kb = kT + (size_t)(b * 128 + (n0 >> 5)) * 1024;
#pragma unroll
    for (int r = 0; r < 16; ++r) {
      const int i = (r & 3) + 8 * (r >> 2) + 4 * h;
      const size_t off = (size_t)(i >> 4) * 512 + ((i >> 3) & 1) * 256 + 8 * l31 + (i & 7);
      qb[off] = f2bfu((acc0[r] + bq[i]) * SCALE_Q);
      kb[off] = f2bfu(acc1[r] + bk[i]);
    }
  } else {
    const int n = n0 + l31;
    const size_t nsub = (size_t)(n >> 4) * 512 + ((size_t)((n >> 3) & 1)) * 256 + (n & 7);
    const size_t bbase = (size_t)b * (1 << 20);
#pragma unroll
    for (int r = 0; r < 16; ++r) {
      const int rp = (r & 3) + 8 * (r >> 2) + 4 * h;
      const int c0 = (w - 1) * 64 + rp;
      const int c1 = c0 + 32;
      vT8[bbase + (size_t)(c0 >> 5) * 131072 + nsub + (c0 & 31) * 8] = f2fp8(acc0[r] + bv[c0]);
      vT8[bbase + (size_t)(c1 >> 5) * 131072 + nsub + (c1 & 31) * 8] = f2fp8(acc1[r] + bv[c1]);
    }
  }
}

// ---- flash attention: 8-wave coop, LEAN registers, 8 waves/SIMD ------------
// r10 structure (verified correct) with launch_bounds(512,8): acc = one
// f32x16/wave (16 AGPR), no reg-prefetch -> total regs <= 64 so FOUR blocks
// co-reside per CU. TLP (8 waves/SIMD) hides the softmax/barrier shadows that
// ILP attempts (r11-r19) could not.
__global__ __launch_bounds__(512, 8) void flash_coop(
    const ushort* __restrict__ qT, const ushort* __restrict__ kT,
    const unsigned char* __restrict__ vT8, const float* __restrict__ x,
    const float* __restrict__ gamma, float* __restrict__ out) {
  __shared__ __align__(16) unsigned char pbuf[32 * 264];  // P fp8 [q][m_local]
  __shared__ float mlds[264];  // per-wave rowmax  [w*33 + q]
  __shared__ float slds[264];  // per-wave rowsum  [w*33 + q]

  const int tid = threadIdx.x;
  const int lane = tid & 63;
  const int w = tid >> 6;
  const int q = lane & 31;
  const int h = lane >> 5;

  const int wg = blockIdx.x;
  const int xcd = wg & 7;
  const int b = xcd >> 1;
  const int nt = ((xcd & 1) << 6) + (wg >> 3);
  const int n0 = nt * 32;

  const ushort* qb = qT + (size_t)(b * 128 + nt) * 1024 + lane * 8;
  const bf16x8 qf0 = *reinterpret_cast<const bf16x8*>(qb);
  const bf16x8 qf1 = *reinterpret_cast<const bf16x8*>(qb + 512);

  const ushort* ktb = kT + (size_t)b * 128 * 1024;
  // ct-major V: wave w owns ct=w; fragment for key-block nt2 at +nt2*512
  const unsigned char* vtb = vT8 + ((size_t)b << 20) + (size_t)w * 131072 + lane * 8;

  f32x16 acc = zero16();
  float m_run = -1e30f, l_run = 0.0f;

  for (int it = 0; it < 16; ++it) {
    // ---- S phase: this wave's 32 keys ----
    const ushort* kc = ktb + (size_t)(it * 8 + w) * 1024 + lane * 8;
    const bf16x8 kf0 = *reinterpret_cast<const bf16x8*>(kc);
    const bf16x8 kf1 = *reinterpret_cast<const bf16x8*>(kc + 512);
    f32x16 st = zero16();
    __builtin_amdgcn_s_setprio(1);
    st = __builtin_amdgcn_mfma_f32_32x32x16_bf16(kf0, qf0, st, 0, 0, 0);
    st = __builtin_amdgcn_mfma_f32_32x32x16_bf16(kf1, qf1, st, 0, 0, 0);
    __builtin_amdgcn_s_setprio(0);

    // per-wave rowmax over its 32 keys
    float m0 = max3f(st[0], st[1], st[2]);
    float m1 = max3f(st[3], st[4], st[5]);
    float m2 = max3f(st[6], st[7], st[8]);
    float m3 = max3f(st[9], st[10], st[11]);
    m0 = max3f(st[12], st[13], m0);
    m1 = max3f(st[14], st[15], m1);
    float mx = max3f(m0, m1, fmaxf(m2, m3));
    float sw1 = mx, sw2 = mx;
    perm32swap_f(sw1, sw2);
    const float wmax = fmaxf(sw1, sw2);
    if (lane < 32) mlds[w * 33 + q] = wmax;
    __syncthreads();  // barrier 1: rowmaxes visible; pbuf(it-1) fully consumed

    // block-wide tile max (uniform per q across all waves)
    float tmax = mlds[q];
#pragma unroll
    for (int i = 1; i < 8; ++i) tmax = fmaxf(tmax, mlds[i * 33 + q]);

    // deferred-max online update (block-uniform decision)
    if (__any(tmax > m_run + 8.0f)) {
      const float mnew = fmaxf(m_run, tmax);
      const float f = __builtin_amdgcn_exp2f(m_run - mnew);
#pragma unroll
      for (int r = 0; r < 16; ++r) acc[r] *= f;
      l_run *= f;
      m_run = mnew;
    }

    // p = exp2(s - m); per-wave partial row sum
#pragma unroll
    for (int r = 0; r < 16; ++r) st[r] = __builtin_amdgcn_exp2f(st[r] - m_run);
    float s0 = ((st[0] + st[1]) + (st[2] + st[3])) +
               ((st[4] + st[5]) + (st[6] + st[7]));
    float s1 = ((st[8] + st[9]) + (st[10] + st[11])) +
               ((st[12] + st[13]) + (st[14] + st[15]));
    float pssum = s0 + s1;
    float pa = pssum, pb = pssum;
    perm32swap_f(pa, pb);
    pssum = pa + pb;
    if (lane < 32) slds[w * 33 + q] = pssum;

    // pack P -> fp8 into pbuf[q][m_local]; m_local = w*32 + rg*8 + 4h + j
#pragma unroll
    for (int rg = 0; rg < 4; ++rg) {
      const int pk = pack4_fp8(st[rg * 4], st[rg * 4 + 1], st[rg * 4 + 2], st[rg * 4 + 3]);
      *reinterpret_cast<int*>(&pbuf[q * 264 + w * 32 + rg * 8 + h * 4]) = pk;
    }
    __syncthreads();  // barrier 2: P + sums visible

    // l update (each wave computes identically)
    float tsum = slds[q];
#pragma unroll
    for (int i = 1; i < 8; ++i) tsum += slds[i * 33 + q];
    l_run += tsum;

    // ---- PV phase: this wave's 32 channels over 256 keys (contiguous V) ----
    const unsigned char* vc = vtb + (size_t)(it * 16) * 512;
    __builtin_amdgcn_s_setprio(1);
#pragma unroll
    for (int kt = 0; kt < 16; ++kt) {
      const long vf = *reinterpret_cast<const long*>(vc + (size_t)kt * 512);
      const long pfr = *reinterpret_cast<const long*>(&pbuf[q * 264 + kt * 16 + h * 8]);
      acc = __builtin_amdgcn_mfma_f32_32x32x16_fp8_fp8(vf, pfr, acc, 0, 0, 0);
    }
    __builtin_amdgcn_s_setprio(0);
  }

  // ---- epilogue: out = gamma * O/l + x ----
  const float g = gamma[0];
  const float linv = 1.0f / l_run;
#pragma unroll
  for (int r = 0; r < 16; ++r) {
    const int c = w * 32 + (r & 3) + 8 * (r >> 2) + 4 * h;
    const size_t idx = ((size_t)b * CC + c) * NN + n0 + q;
    out[idx] = g * acc[r] * linv + x[idx];
  }
}

extern "C" void kernel_launch(void* const* d_in, const int* in_sizes, int n_in,
                              void* d_out, int out_size, void* d_ws, size_t ws_size,
                              hipStream_t stream) {
  const float* x = (const float*)d_in[0];
  const float* Wq = (const float*)d_in[1];
  const float* bq = (const float*)d_in[2];
  const float* Wk = (const float*)d_in[3];
  const float* bk = (const float*)d_in[4];
  const float* Wv = (const float*)d_in[5];
  const float* bv = (const float*)d_in[6];
  const float* gamma = (const float*)d_in[7];
  float* out = (float*)d_out;

  ushort* qT = (ushort*)d_ws;                          // B*128*1024 bf16
  ushort* kT = qT + (size_t)BB * 128 * 1024;           // B*128*1024 bf16
  unsigned char* vT8 = (unsigned char*)(kT + (size_t)BB * 128 * 1024);  // B*1MB fp8
  ushort* wpre = (ushort*)(vT8 + (size_t)BB * (1 << 20));  // 160 KB

  prepack_w<<<dim3(10, 16), dim3(64), 0, stream>>>(Wq, Wk, Wv, wpre);
  proj_lds<<<dim3(BB, NN / 32), dim3(320), 0, stream>>>(
      bq, bk, bv, x, wpre, qT, kT, vT8);
  flash_coop<<<dim3(512), dim3(512), 0, stream>>>(
      qT, kT, vT8, x, gamma, out);
}